// Round 12
// baseline (229.246 us; speedup 1.0000x reference)
//
#include <hip/hip_runtime.h>
#include <hip/hip_bf16.h>

// MHA forward, B=2, S=2048, D=1024, H=16, Dk=64, causal, RoPE. fp32 I/O.
// Internal bf16 MFMA 16x16x32, fp32 accum.
// R12: attn was LDS-pipe + barrier bound (VALU 34%, MFMA 9%, HBM 2%).
//  (a) double-buffered Vt -> ONE __syncthreads per j-iter (was 2);
//  (b) P writes packed b32 (lane-parity pairs + __float22bfloat162_rn):
//      8 DS instrs/proc instead of 16, fewer VALU than manual f2b;
//  (c) rope_tab fused into cvt_all (one fewer launch).
// GEMMs unchanged from R11 (m97 global_load_lds + RoPE table epilogue).

typedef unsigned short u16;
typedef __attribute__((ext_vector_type(8))) short short8;   // 8 bf16 = 4 VGPRs
typedef __attribute__((ext_vector_type(4))) float float4v;  // MFMA C/D

typedef const __attribute__((address_space(1))) void GV;    // global
typedef __attribute__((address_space(3))) void LV;          // LDS

#define VSTR 72   // attn Vt/Ps row stride (u16): 144B rows, ~2-way banks
#define QSCL 0.18033688011112042f   // 0.125 * log2(e)

__device__ __forceinline__ u16 f2b(float f) {
    union { float f; unsigned int i; } t; t.f = f;
    unsigned int r = t.i + 0x7fffu + ((t.i >> 16) & 1u);   // RNE
    return (u16)(r >> 16);
}

// ------- fused fp32->bf16 converter + RoPE cos/sin table -------------------
__global__ __launch_bounds__(256) void cvt_all(
    const float4* __restrict__ x,  const float4* __restrict__ wq,
    const float4* __restrict__ wk, const float4* __restrict__ wv,
    const float4* __restrict__ wo,
    u16* __restrict__ xb, u16* __restrict__ wcat, u16* __restrict__ wob,
    float2* __restrict__ tab)
{
    const int i = blockIdx.x * 256 + threadIdx.x;
    if (i >= 1048576) {                                  // RoPE table tail
        const int j = i - 1048576;                       // 0..65535
        const int pos = j >> 5, fi = j & 31;
        const float freq = exp2f((float)fi * -0.4152410118609203f);
        float sn, cs; sincosf((float)pos * freq, &sn, &cs);
        tab[j] = make_float2(cs, sn);
        return;
    }
    const float4* s; u16* d; int off;
    if (i < 524288) { s = x; d = xb; off = i; }
    else {
        const int widx = i - 524288;
        const int w = widx >> 17, o = widx & 131071;
        switch (w) {
            case 0:  s = wq; d = wcat;              break;
            case 1:  s = wk; d = wcat + (1 << 20);  break;
            case 2:  s = wv; d = wcat + (2 << 20);  break;
            default: s = wo; d = wob;               break;
        }
        off = o;
    }
    float4 a = s[2 * off], b = s[2 * off + 1];
    u16 t[8] = {f2b(a.x), f2b(a.y), f2b(a.z), f2b(a.w),
                f2b(b.x), f2b(b.y), f2b(b.z), f2b(b.w)};
    reinterpret_cast<int4*>(d)[off] = *reinterpret_cast<int4*>(t);
}

// ---------------------------------------------------------------------------
// Y[m][n] = sum_k X[m][k] * W[n][k]; 128(m) x NT*32(n) x 64(k) tiles.
// global_load_lds width=16 staging; 64-elem LDS rows, unit u at phys u^(row&7).
// ROPE=1: route cols to Yq/Yk/Yv, RoPE q,k via table, scale q by QSCL.
// ---------------------------------------------------------------------------
template<int NT, int ROPE, int NBLK>
__global__ __launch_bounds__(256) void gemm_tile(
    const u16* __restrict__ X, const u16* __restrict__ Wb,
    u16* __restrict__ Yq, u16* __restrict__ Yk, u16* __restrict__ Yv,
    float* __restrict__ Yf, const float2* __restrict__ tab)
{
    __shared__ u16 As[128 * 64];
    __shared__ u16 Bs[NT * 32 * 64];

    const int tid  = threadIdx.x;
    const int wave = tid >> 6;
    const int lane = tid & 63;
    const int quad = lane >> 4;
    const int l16  = lane & 15;
    const int wm = (wave >> 1) * 64, wn = (wave & 1) * (NT * 16);
    const int g = blockIdx.x;
    const int rr = g >> 3;
    const int m0 = ((g & 7) * 4 + rr / NBLK) * 128;
    const int n0 = (rr % NBLK) * (NT * 32);
    const int lrow = lane >> 3;
    const int cg8  = (lane & 7) ^ lrow;

    float4v acc[4][NT];
#pragma unroll
    for (int mt = 0; mt < 4; mt++)
#pragma unroll
        for (int nt = 0; nt < NT; nt++) acc[mt][nt] = (float4v){0.f, 0.f, 0.f, 0.f};

    for (int kb = 0; kb < 1024; kb += 64) {
        __syncthreads();
#pragma unroll
        for (int t = 0; t < 4; t++) {
            const int I = wave * 4 + t;
            const u16* gp = X + (size_t)(m0 + I * 8 + lrow) * 1024 + kb + cg8 * 8;
            __builtin_amdgcn_global_load_lds((GV*)gp, (LV*)&As[I * 512], 16, 0, 0);
        }
#pragma unroll
        for (int t = 0; t < NT; t++) {
            const int I = wave * NT + t;
            const u16* gp = Wb + (size_t)(n0 + I * 8 + lrow) * 1024 + kb + cg8 * 8;
            __builtin_amdgcn_global_load_lds((GV*)gp, (LV*)&Bs[I * 512], 16, 0, 0);
        }
        __syncthreads();
#pragma unroll
        for (int ks = 0; ks < 2; ks++) {
            const int su = ((ks * 4 + quad) ^ (l16 & 7)) * 8;
            short8 af[4], bf[NT];
#pragma unroll
            for (int t = 0; t < 4; t++)
                af[t] = *reinterpret_cast<const short8*>(&As[(wm + t * 16 + l16) * 64 + su]);
#pragma unroll
            for (int t = 0; t < NT; t++)
                bf[t] = *reinterpret_cast<const short8*>(&Bs[(wn + t * 16 + l16) * 64 + su]);
#pragma unroll
            for (int mt = 0; mt < 4; mt++)
#pragma unroll
                for (int nt = 0; nt < NT; nt++)
                    acc[mt][nt] = __builtin_amdgcn_mfma_f32_16x16x32_bf16(af[mt], bf[nt], acc[mt][nt], 0, 0, 0);
        }
    }

    if (ROPE) {
#pragma unroll
        for (int nt = 0; nt < NT; nt++) {
            const int cg = n0 + wn + nt * 16 + l16;
            const int buf = cg >> 10;
            const int c = cg & 1023;
            u16* dst = (buf == 0) ? Yq : ((buf == 1) ? Yk : Yv);
            const bool rp = (buf < 2);
            const float scl = (buf == 0) ? QSCL : 1.0f;
            const int fi = (cg & 63) >> 1;
#pragma unroll
            for (int mt = 0; mt < 4; mt++)
#pragma unroll
                for (int r = 0; r < 4; r++) {
                    const int row = m0 + wm + mt * 16 + quad * 4 + r;
                    float v = acc[mt][nt][r];
                    if (rp) {
                        const float2 t = tab[((row & 2047) << 5) + fi];
                        const float partner = __shfl_xor(v, 1);
                        v = (l16 & 1) ? fmaf(v, t.x,  partner * t.y)
                                      : fmaf(v, t.x, -partner * t.y);
                    }
                    dst[(size_t)row * 1024 + c] = f2b(v * scl);
                }
        }
    } else {
#pragma unroll
        for (int nt = 0; nt < NT; nt++) {
            const int col = n0 + wn + nt * 16 + l16;
#pragma unroll
            for (int mt = 0; mt < 4; mt++)
#pragma unroll
                for (int r = 0; r < 4; r++) {
                    const int row = m0 + wm + mt * 16 + quad * 4 + r;
                    Yf[(size_t)row * 1024 + col] = acc[mt][nt][r];
                }
        }
    }
}

// ---------------------------------------------------------------------------
// Flash causal attention, paired q-tiles (qtA, 31-qtA), unnormalized softmax
// (q pre-scaled 0.125*log2e -> p = exp2f(s)). K frags direct from global,
// prefetched. Vt DOUBLE-BUFFERED (1 barrier/iter). P written as packed b32
// (lane-parity col pairs). XCD grouping keeps a (b,h)'s K/V in one L2.
// O aliases Q (block-disjoint regions).
// ---------------------------------------------------------------------------
__global__ __launch_bounds__(256, 2) void attn_kernel(
    const u16* Q, const u16* __restrict__ K,
    const u16* __restrict__ V, u16* O)
{
    __shared__ u16 Vt[2][64 * VSTR];        // Vt[buf][d][s^((d>>4)<<4)]
    __shared__ u16 Ps[4 * 16 * VSTR];

    const int tid  = threadIdx.x;
    const int wave = tid >> 6;
    const int lane = tid & 63;
    const int quad = lane >> 4;
    const int l16  = lane & 15;
    const int g = blockIdx.x;
    const int xcd = g & 7, slot = g >> 3;
    const int G = (slot >> 4) * 8 + xcd;    // 0..31 = (b,h) group
    const int qtA = slot & 15;
    const int qtB = 31 - qtA;
    const int b = G & 1, h = G >> 1;
    const size_t base = ((size_t)b * 2048) * 1024 + (size_t)h * 64;

    short8 qfA[2], qfB[2];
    {
        const size_t ra = base + (size_t)(qtA * 64 + wave * 16 + l16) * 1024;
        qfA[0] = *reinterpret_cast<const short8*>(Q + ra + quad * 8);
        qfA[1] = *reinterpret_cast<const short8*>(Q + ra + 32 + quad * 8);
        const size_t rb = base + (size_t)(qtB * 64 + wave * 16 + l16) * 1024;
        qfB[0] = *reinterpret_cast<const short8*>(Q + rb + quad * 8);
        qfB[1] = *reinterpret_cast<const short8*>(Q + rb + 32 + quad * 8);
    }

    float4v oA[4], oB[4];
#pragma unroll
    for (int i = 0; i < 4; i++) { oA[i] = (float4v){0.f,0.f,0.f,0.f}; oB[i] = (float4v){0.f,0.f,0.f,0.f}; }
    float sA[4] = {0.f,0.f,0.f,0.f}, sB[4] = {0.f,0.f,0.f,0.f};

    u16* Pw = Ps + wave * 16 * VSTR;
    const int srow = tid >> 2;             // 0..63 (coalesced V loads)
    const int cb   = (tid & 3) << 4;       // 0,16,32,48
    const int sxw  = srow ^ cb;            // swizzled s

    const u16* Vbase = V + base + (size_t)srow * 1024 + cb;
    const u16* kbase = K + base + (size_t)l16 * 1024 + quad * 8;

    short8 kn[4][2], kc[4][2], vf[4][2];
    int4 vr0, vr1;

    auto vstage = [&](int bufi, const int4& a4, const int4& c4) {
        const u16* a = reinterpret_cast<const u16*>(&a4);
        const u16* c = reinterpret_cast<const u16*>(&c4);
        u16* vt = Vt[bufi];
#pragma unroll
        for (int e = 0; e < 8; e++) vt[(cb + e) * VSTR + sxw] = a[e];
#pragma unroll
        for (int e = 0; e < 8; e++) vt[(cb + 8 + e) * VSTR + sxw] = c[e];
    };

    // prologue: V0 -> LDS buf0; V1 -> regs; K0 frags -> kn
    vr0 = *reinterpret_cast<const int4*>(Vbase);
    vr1 = *reinterpret_cast<const int4*>(Vbase + 8);
    vstage(0, vr0, vr1);
    vr0 = *reinterpret_cast<const int4*>(Vbase + 65536);      // qtB >= 16 always
    vr1 = *reinterpret_cast<const int4*>(Vbase + 65536 + 8);
#pragma unroll
    for (int nt = 0; nt < 4; nt++)
#pragma unroll
        for (int ks = 0; ks < 2; ks++)
            kn[nt][ks] = *reinterpret_cast<const short8*>(kbase + (size_t)(nt * 16) * 1024 + ks * 32);

    auto proc = [&](const short8 (&qf)[2], float4v (&oc)[4], float (&sr)[4], bool diag) {
        float4v sacc[4];
#pragma unroll
        for (int nt = 0; nt < 4; nt++) {
            sacc[nt] = (float4v){0.f, 0.f, 0.f, 0.f};
#pragma unroll
            for (int ks = 0; ks < 2; ks++)
                sacc[nt] = __builtin_amdgcn_mfma_f32_16x16x32_bf16(qf[ks], kc[nt][ks], sacc[nt], 0, 0, 0);
        }
        const bool odd = l16 & 1;
        const int c0 = (l16 & ~1) + (odd ? 32 : 0);
#pragma unroll
        for (int r = 0; r < 4; r++) {
            const int qloc = wave * 16 + quad * 4 + r;
            float pv[4];
#pragma unroll
            for (int nt = 0; nt < 4; nt++) {
                float s = sacc[nt][r];                       // log2-domain
                if (diag && (nt * 16 + l16 > qloc)) s = -1e30f;
                const float p = exp2f(s);                    // masked -> 0
                sr[r] += p;
                pv[nt] = p;
            }
            float sh[4];
#pragma unroll
            for (int nt = 0; nt < 4; nt++) sh[nt] = __shfl_xor(pv[nt], 1);
            // even lanes: cols (l16, l16+1) of nt 0/1; odd: cols-1 of nt 2/3
            const float a0 = odd ? sh[2] : pv[0], b0 = odd ? pv[2] : sh[0];
            const float a1 = odd ? sh[3] : pv[1], b1 = odd ? pv[3] : sh[1];
            __hip_bfloat162 pk0 = __float22bfloat162_rn(make_float2(a0, b0));
            __hip_bfloat162 pk1 = __float22bfloat162_rn(make_float2(a1, b1));
            u16* prow = &Pw[(quad * 4 + r) * VSTR];
            *reinterpret_cast<__hip_bfloat162*>(&prow[c0])      = pk0;
            *reinterpret_cast<__hip_bfloat162*>(&prow[c0 + 16]) = pk1;
        }
        __builtin_amdgcn_wave_barrier();   // P write->read is wave-local
#pragma unroll
        for (int ks = 0; ks < 2; ks++) {
            short8 pf = *reinterpret_cast<const short8*>(&Pw[l16 * VSTR + ks * 32 + quad * 8]);
#pragma unroll
            for (int dt = 0; dt < 4; dt++)
                oc[dt] = __builtin_amdgcn_mfma_f32_16x16x32_bf16(pf, vf[dt][ks], oc[dt], 0, 0, 0);
        }
        __builtin_amdgcn_wave_barrier();
    };

    for (int j = 0; j <= qtB; j++) {
        __syncthreads();   // buf j&1 writes visible; prior reads of buf (j+1)&1 done
        {
            const u16* vt = Vt[j & 1];
#pragma unroll
            for (int nt = 0; nt < 4; nt++)
#pragma unroll
                for (int ks = 0; ks < 2; ks++)
                    vf[nt][ks] = *reinterpret_cast<const short8*>(&vt[(nt * 16 + l16) * VSTR + ((ks * 32 + quad * 8) ^ (nt << 4))]);
        }
#pragma unroll
        for (int nt = 0; nt < 4; nt++)
#pragma unroll
            for (int ks = 0; ks < 2; ks++) kc[nt][ks] = kn[nt][ks];
        if (j < qtB) {
            vstage((j + 1) & 1, vr0, vr1);               // V tile j+1 -> LDS
            if (j + 2 <= qtB) {                          // V tile j+2 -> regs
                vr0 = *reinterpret_cast<const int4*>(Vbase + (size_t)(j + 2) * 65536);
                vr1 = *reinterpret_cast<const int4*>(Vbase + (size_t)(j + 2) * 65536 + 8);
            }
            const u16* kb2 = kbase + (size_t)(j + 1) * 65536;
#pragma unroll
            for (int nt = 0; nt < 4; nt++)
#pragma unroll
                for (int ks = 0; ks < 2; ks++)
                    kn[nt][ks] = *reinterpret_cast<const short8*>(kb2 + (size_t)(nt * 16) * 1024 + ks * 32);
        }
        if (j <= qtA) proc(qfA, oA, sA, j == qtA);
        proc(qfB, oB, sB, j == qtB);
    }

    // epilogue: one cross-lane sum reduction, normalize, write
#pragma unroll
    for (int r = 0; r < 4; r++) {
        float la = sA[r], lb = sB[r];
#pragma unroll
        for (int msk = 1; msk < 16; msk <<= 1) { la += __shfl_xor(la, msk); lb += __shfl_xor(lb, msk); }
        const float invA = 1.0f / la, invB = 1.0f / lb;
        const int rloc = wave * 16 + quad * 4 + r;
        const size_t rowA = base + (size_t)(qtA * 64 + rloc) * 1024;
        const size_t rowB = base + (size_t)(qtB * 64 + rloc) * 1024;
#pragma unroll
        for (int dt = 0; dt < 4; dt++) {
            O[rowA + dt * 16 + l16] = f2b(oA[dt][r] * invA);
            O[rowB + dt * 16 + l16] = f2b(oB[dt][r] * invB);
        }
    }
}

// ---------------------------------------------------------------------------
extern "C" void kernel_launch(void* const* d_in, const int* in_sizes, int n_in,
                              void* d_out, int out_size, void* d_ws, size_t ws_size,
                              hipStream_t stream) {
    (void)in_sizes; (void)n_in; (void)out_size; (void)ws_size;
    const float* x  = (const float*)d_in[0];
    const float* wq = (const float*)d_in[1];
    const float* wk = (const float*)d_in[2];
    const float* wv = (const float*)d_in[3];
    const float* wo = (const float*)d_in[4];

    const size_t MN = (size_t)4096 * 1024;

    // d_out (16MB): xb (8MB) + wcat (6MB) + rope table (512KB tail); all
    // consumed before the final fp32 GEMM overwrites d_out.
    u16* xb   = (u16*)d_out;
    u16* wcat = xb + MN;
    float2* tab = (float2*)(wcat + (size_t)3072 * 1024);
    u16* qbuf = (u16*)d_ws;                 // also attention output
    u16* kbuf = qbuf + MN;
    u16* vbuf = kbuf + MN;
    u16* wob  = vbuf + MN;                  // ws total: 26MB

    cvt_all<<<4352, 256, 0, stream>>>((const float4*)x, (const float4*)wq,
                                      (const float4*)wk, (const float4*)wv,
                                      (const float4*)wo, xb, wcat, wob, tab);
    gemm_tile<4, 1, 24><<<768, 256, 0, stream>>>(xb, wcat, qbuf, kbuf, vbuf, nullptr, tab);
    attn_kernel<<<512, 256, 0, stream>>>(qbuf, kbuf, vbuf, qbuf);
    gemm_tile<2, 0, 16><<<512, 256, 0, stream>>>(qbuf, wob, nullptr, nullptr, nullptr, (float*)d_out, nullptr);
}